// Round 8
// baseline (314.548 us; speedup 1.0000x reference)
//
#include <hip/hip_runtime.h>
#include <math.h>

#define N_NODES 50000
#define N_EDGES 800000
#define F_IN 128
#define HIDDEN 256
#define N_CLASSES 40

#define CHUNK 256
#define NCHUNK ((N_NODES + CHUNK - 1) / CHUNK)  // 196

typedef __attribute__((ext_vector_type(8))) short bf16x8;
typedef __attribute__((ext_vector_type(4))) float f32x4;
typedef __attribute__((ext_vector_type(8))) unsigned short u16x8;

// ---------------- bf16 helpers ----------------

__device__ __forceinline__ float bf2f(unsigned short u) {
    unsigned int t = ((unsigned int)u) << 16;
    float f;
    __builtin_memcpy(&f, &t, 4);
    return f;
}

__device__ __forceinline__ unsigned short f2bf(float f) {
    unsigned int t;
    __builtin_memcpy(&t, &f, 4);
    unsigned int r = (t + 0x7fffu + ((t >> 16) & 1u)) >> 16;  // RNE
    return (unsigned short)r;
}

// ---------------- CSR build ----------------

__global__ void zero_counts(int* __restrict__ counts) {
    int i = blockIdx.x * blockDim.x + threadIdx.x;
    if (i < N_NODES) counts[i] = 0;
}

// edge_index arrives as int32 (JAX x64-disabled downgrades int64)
__global__ void count_kernel(const int* __restrict__ dst, int* __restrict__ counts) {
    int e = blockIdx.x * blockDim.x + threadIdx.x;
    if (e < N_EDGES) {
        int d = dst[e];
        d = (d < 0) ? 0 : (d >= N_NODES ? N_NODES - 1 : d);
        atomicAdd(&counts[d], 1);
    }
}

__global__ __launch_bounds__(256) void scan_partials(const int* __restrict__ counts,
                                                     int* __restrict__ bsum) {
    __shared__ int red[4];
    int b = blockIdx.x;
    int i = b * CHUNK + threadIdx.x;
    int v = (i < N_NODES) ? counts[i] : 0;
    for (int off = 32; off > 0; off >>= 1) v += __shfl_down(v, off, 64);
    int wave = threadIdx.x >> 6;
    int lane = threadIdx.x & 63;
    if (lane == 0) red[wave] = v;
    __syncthreads();
    if (threadIdx.x == 0) bsum[b] = red[0] + red[1] + red[2] + red[3];
}

__global__ __launch_bounds__(256) void scan_bsums(int* __restrict__ bsum,
                                                  int* __restrict__ boff) {
    __shared__ int s[256];
    int tid = threadIdx.x;
    int v = (tid < NCHUNK) ? bsum[tid] : 0;
    s[tid] = v;
    __syncthreads();
    for (int off = 1; off < 256; off <<= 1) {
        int t = (tid >= off) ? s[tid - off] : 0;
        __syncthreads();
        s[tid] += t;
        __syncthreads();
    }
    if (tid < NCHUNK) boff[tid] = s[tid] - v;
    if (tid == NCHUNK - 1) boff[NCHUNK] = s[tid];
}

__global__ __launch_bounds__(256) void scan_apply(const int* __restrict__ counts,
                                                  const int* __restrict__ boff,
                                                  int* __restrict__ row_off,
                                                  int* __restrict__ cursor,
                                                  float* __restrict__ inv_deg) {
    __shared__ int s[256];
    int b = blockIdx.x;
    int tid = threadIdx.x;
    int i = b * CHUNK + tid;
    int v = (i < N_NODES) ? counts[i] : 0;
    s[tid] = v;
    __syncthreads();
    for (int off = 1; off < 256; off <<= 1) {
        int t = (tid >= off) ? s[tid - off] : 0;
        __syncthreads();
        s[tid] += t;
        __syncthreads();
    }
    if (i < N_NODES) {
        int excl = boff[b] + s[tid] - v;
        row_off[i] = excl;
        cursor[i] = excl;
        inv_deg[i] = 1.0f / fmaxf((float)v, 1.0f);
        if (i == N_NODES - 1) row_off[N_NODES] = excl + v;
    }
}

__global__ void fill_kernel(const int* __restrict__ ei, int* __restrict__ cursor,
                            int* __restrict__ csr_src) {
    int e = blockIdx.x * blockDim.x + threadIdx.x;
    if (e < N_EDGES) {
        int s = ei[e];
        int d = ei[N_EDGES + e];
        s = (s < 0) ? 0 : (s >= N_NODES ? N_NODES - 1 : s);
        d = (d < 0) ? 0 : (d >= N_NODES ? N_NODES - 1 : d);
        int pos = atomicAdd(&cursor[d], 1);
        if (pos >= 0 && pos < N_EDGES) csr_src[pos] = s;
    }
}

// ---------------- x -> bf16 conversion ----------------

__global__ void conv_x16(const float* __restrict__ x, unsigned short* __restrict__ x16) {
    int i = blockIdx.x * blockDim.x + threadIdx.x;  // 4 elems/thread
    if (i < N_NODES * F_IN / 4) {
        float4 v = reinterpret_cast<const float4*>(x)[i];
        ushort4 o;
        o.x = f2bf(v.x); o.y = f2bf(v.y); o.z = f2bf(v.z); o.w = f2bf(v.w);
        reinterpret_cast<ushort4*>(x16)[i] = o;
    }
}

// ---------------- weight packs ----------------

__global__ void pack_w1(const float* __restrict__ W1l, const float* __restrict__ W1r,
                        unsigned short* __restrict__ Wpk) {
    int n = blockIdx.x;
    int k = threadIdx.x;
    float v = (k < F_IN) ? W1l[(size_t)k * HIDDEN + n] : W1r[(size_t)(k - F_IN) * HIDDEN + n];
    Wpk[(size_t)n * 256 + k] = f2bf(v);
}

__global__ void pack_w2(const float* __restrict__ W2l, const float* __restrict__ W2r,
                        unsigned short* __restrict__ Wpk2) {
    int n = blockIdx.x;   // 0..63
    int k = threadIdx.x;  // 0..511
    float v = 0.f;
    if (n < N_CLASSES)
        v = (k < HIDDEN) ? W2l[(size_t)k * N_CLASSES + n] : W2r[(size_t)(k - HIDDEN) * N_CLASSES + n];
    Wpk2[(size_t)n * 512 + k] = f2bf(v);
}

// ---------------- layer 1: quarter-wave gather + MFMA + relu -> h16 ----------------
// 256 threads (4 waves), 16 nodes/block. Quarter-wave (16 lanes x 16B) per edge:
// 4 edges in parallel per wave, x4 unroll = 16 edges (4x16B loads/lane) in flight.

#define AS1_STRIDE 264

__global__ __launch_bounds__(256) void gemm1_fused(
    const unsigned short* __restrict__ x16, const int* __restrict__ row_off,
    const int* __restrict__ csr_src, const float* __restrict__ inv_deg,
    const unsigned short* __restrict__ Wpk, const float* __restrict__ b1,
    unsigned short* __restrict__ h16) {
    __shared__ __align__(16) unsigned short As[16][AS1_STRIDE];
    int n0 = blockIdx.x * 16;
    int tid = threadIdx.x;
    int wave = tid >> 6;
    int lane = tid & 63;
    int q = lane >> 4;   // quarter 0..3
    int fl = lane & 15;  // feature lane: 8 bf16 at fl*8

    for (int j = wave; j < 16; j += 4) {
        int n = n0 + j;
        int e0 = row_off[n], e1 = row_off[n + 1];
        int deg = e1 - e0;
        float a[8] = {0.f, 0.f, 0.f, 0.f, 0.f, 0.f, 0.f, 0.f};
        int it = 0;
        for (; it + 15 < deg; it += 16) {  // 16 edges: 4 quarters x 4 unroll
            int sA = csr_src[e0 + it + q];
            int sB = csr_src[e0 + it + 4 + q];
            int sC = csr_src[e0 + it + 8 + q];
            int sD = csr_src[e0 + it + 12 + q];
            u16x8 vA = *reinterpret_cast<const u16x8*>(x16 + (size_t)sA * F_IN + fl * 8);
            u16x8 vB = *reinterpret_cast<const u16x8*>(x16 + (size_t)sB * F_IN + fl * 8);
            u16x8 vC = *reinterpret_cast<const u16x8*>(x16 + (size_t)sC * F_IN + fl * 8);
            u16x8 vD = *reinterpret_cast<const u16x8*>(x16 + (size_t)sD * F_IN + fl * 8);
#pragma unroll
            for (int i = 0; i < 8; ++i)
                a[i] += (bf2f(vA[i]) + bf2f(vB[i])) + (bf2f(vC[i]) + bf2f(vD[i]));
        }
        for (; it + 3 < deg; it += 4) {  // 4 edges
            int s = csr_src[e0 + it + q];
            u16x8 v = *reinterpret_cast<const u16x8*>(x16 + (size_t)s * F_IN + fl * 8);
#pragma unroll
            for (int i = 0; i < 8; ++i) a[i] += bf2f(v[i]);
        }
        if (it + q < deg) {  // tail 0..3 edges, predicated per quarter
            int s = csr_src[e0 + it + q];
            u16x8 v = *reinterpret_cast<const u16x8*>(x16 + (size_t)s * F_IN + fl * 8);
#pragma unroll
            for (int i = 0; i < 8; ++i) a[i] += bf2f(v[i]);
        }
#pragma unroll
        for (int i = 0; i < 8; ++i) {
            a[i] += __shfl_xor(a[i], 16);
            a[i] += __shfl_xor(a[i], 32);
        }
        if (lane < 16) {
            float id = inv_deg[n];
            u16x8 m;
#pragma unroll
            for (int i = 0; i < 8; ++i) m[i] = f2bf(a[i] * id);
            *reinterpret_cast<u16x8*>(&As[j][fl * 8]) = m;
            *reinterpret_cast<u16x8*>(&As[j][F_IN + fl * 8]) =
                *reinterpret_cast<const u16x8*>(x16 + (size_t)n * F_IN + fl * 8);
        }
    }
    __syncthreads();

    // ---- MFMA phase (m89-verified layout) ----
    int mrow = lane & 15;
    int kg = lane >> 4;
    f32x4 acc0 = {0.f, 0.f, 0.f, 0.f};
    f32x4 acc1 = {0.f, 0.f, 0.f, 0.f};
    f32x4 acc2 = {0.f, 0.f, 0.f, 0.f};
    f32x4 acc3 = {0.f, 0.f, 0.f, 0.f};
    const unsigned short* wp = Wpk + ((size_t)(wave * 4) * 16 + mrow) * 256 + kg * 8;
#pragma unroll
    for (int ks = 0; ks < 8; ++ks) {
        bf16x8 a = *reinterpret_cast<const bf16x8*>(&As[mrow][ks * 32 + kg * 8]);
        bf16x8 b0 = *reinterpret_cast<const bf16x8*>(wp + 0 * 16 * 256 + ks * 32);
        bf16x8 b1f = *reinterpret_cast<const bf16x8*>(wp + 1 * 16 * 256 + ks * 32);
        bf16x8 b2 = *reinterpret_cast<const bf16x8*>(wp + 2 * 16 * 256 + ks * 32);
        bf16x8 b3 = *reinterpret_cast<const bf16x8*>(wp + 3 * 16 * 256 + ks * 32);
        acc0 = __builtin_amdgcn_mfma_f32_16x16x32_bf16(a, b0, acc0, 0, 0, 0);
        acc1 = __builtin_amdgcn_mfma_f32_16x16x32_bf16(a, b1f, acc1, 0, 0, 0);
        acc2 = __builtin_amdgcn_mfma_f32_16x16x32_bf16(a, b2, acc2, 0, 0, 0);
        acc3 = __builtin_amdgcn_mfma_f32_16x16x32_bf16(a, b3, acc3, 0, 0, 0);
    }
    f32x4 accs[4] = {acc0, acc1, acc2, acc3};
#pragma unroll
    for (int i = 0; i < 4; ++i) {
        int n = (wave * 4 + i) * 16 + mrow;
        float bb = b1[n];
#pragma unroll
        for (int r = 0; r < 4; ++r) {
            int row = kg * 4 + r;
            h16[(size_t)(n0 + row) * HIDDEN + n] = f2bf(fmaxf(accs[i][r] + bb, 0.f));
        }
    }
}

// ---------------- layer 2: half-wave gather (x8 unroll) + MFMA + log_softmax ----------------
// 512 threads (8 waves), 32 nodes/block. Half-wave (32 lanes x 16B) per edge;
// x8 unroll = 16 edges (8x16B loads/lane) in flight.

#define NB2 32
#define AS2_STRIDE 520

__global__ __launch_bounds__(512) void gemm2_fused(
    const unsigned short* __restrict__ h16, const int* __restrict__ row_off,
    const int* __restrict__ csr_src, const float* __restrict__ inv_deg,
    const unsigned short* __restrict__ Wpk2, const float* __restrict__ b2,
    float* __restrict__ out) {
    __shared__ __align__(16) unsigned short As[NB2][AS2_STRIDE];
    __shared__ float out_s[NB2][40];
    __shared__ float lse[NB2];
    int n0 = blockIdx.x * NB2;
    int tid = threadIdx.x;
    int wave = tid >> 6;
    int lane = tid & 63;
    int half = lane >> 5;
    int fl = lane & 31;

    for (int j = wave; j < NB2; j += 8) {
        int n = n0 + j;
        if (n < N_NODES) {
            int e0 = row_off[n], e1 = row_off[n + 1];
            int deg = e1 - e0;
            float a[8] = {0.f, 0.f, 0.f, 0.f, 0.f, 0.f, 0.f, 0.f};
            int it = 0;
            for (; it + 15 < deg; it += 16) {  // 16 edges: 2 halves x 8 unroll
                int s0 = csr_src[e0 + it + half];
                int s1 = csr_src[e0 + it + 2 + half];
                int s2 = csr_src[e0 + it + 4 + half];
                int s3 = csr_src[e0 + it + 6 + half];
                int s4 = csr_src[e0 + it + 8 + half];
                int s5 = csr_src[e0 + it + 10 + half];
                int s6 = csr_src[e0 + it + 12 + half];
                int s7 = csr_src[e0 + it + 14 + half];
                u16x8 v0 = *reinterpret_cast<const u16x8*>(h16 + (size_t)s0 * HIDDEN + fl * 8);
                u16x8 v1 = *reinterpret_cast<const u16x8*>(h16 + (size_t)s1 * HIDDEN + fl * 8);
                u16x8 v2 = *reinterpret_cast<const u16x8*>(h16 + (size_t)s2 * HIDDEN + fl * 8);
                u16x8 v3 = *reinterpret_cast<const u16x8*>(h16 + (size_t)s3 * HIDDEN + fl * 8);
                u16x8 v4 = *reinterpret_cast<const u16x8*>(h16 + (size_t)s4 * HIDDEN + fl * 8);
                u16x8 v5 = *reinterpret_cast<const u16x8*>(h16 + (size_t)s5 * HIDDEN + fl * 8);
                u16x8 v6 = *reinterpret_cast<const u16x8*>(h16 + (size_t)s6 * HIDDEN + fl * 8);
                u16x8 v7 = *reinterpret_cast<const u16x8*>(h16 + (size_t)s7 * HIDDEN + fl * 8);
#pragma unroll
                for (int i = 0; i < 8; ++i)
                    a[i] += ((bf2f(v0[i]) + bf2f(v1[i])) + (bf2f(v2[i]) + bf2f(v3[i]))) +
                            ((bf2f(v4[i]) + bf2f(v5[i])) + (bf2f(v6[i]) + bf2f(v7[i])));
            }
            for (; it + 1 < deg; it += 2) {  // 2 edges
                int s = csr_src[e0 + it + half];
                u16x8 v = *reinterpret_cast<const u16x8*>(h16 + (size_t)s * HIDDEN + fl * 8);
#pragma unroll
                for (int i = 0; i < 8; ++i) a[i] += bf2f(v[i]);
            }
            if (it + half < deg) {  // odd tail, half 0 only
                int s = csr_src[e0 + it + half];
                u16x8 v = *reinterpret_cast<const u16x8*>(h16 + (size_t)s * HIDDEN + fl * 8);
#pragma unroll
                for (int i = 0; i < 8; ++i) a[i] += bf2f(v[i]);
            }
#pragma unroll
            for (int i = 0; i < 8; ++i) a[i] += __shfl_xor(a[i], 32);
            if (lane < 32) {
                float id = inv_deg[n];
                u16x8 m;
#pragma unroll
                for (int i = 0; i < 8; ++i) m[i] = f2bf(a[i] * id);
                *reinterpret_cast<u16x8*>(&As[j][fl * 8]) = m;
                *reinterpret_cast<u16x8*>(&As[j][HIDDEN + fl * 8]) =
                    *reinterpret_cast<const u16x8*>(h16 + (size_t)n * HIDDEN + fl * 8);
            }
        } else {
            if (lane < 32) {
                u16x8 z = {0, 0, 0, 0, 0, 0, 0, 0};
                *reinterpret_cast<u16x8*>(&As[j][fl * 8]) = z;
                *reinterpret_cast<u16x8*>(&As[j][HIDDEN + fl * 8]) = z;
            }
        }
    }
    __syncthreads();

    // ---- MFMA phase ----
    int mrow = lane & 15;
    int kg = lane >> 4;
    int mt = wave >> 2;  // 0..1
    int nt = wave & 3;   // 0..3
    f32x4 acc = {0.f, 0.f, 0.f, 0.f};
    const unsigned short* wp = Wpk2 + ((size_t)(nt * 16 + mrow)) * 512 + kg * 8;
#pragma unroll
    for (int ks = 0; ks < 16; ++ks) {
        bf16x8 a = *reinterpret_cast<const bf16x8*>(&As[mt * 16 + mrow][ks * 32 + kg * 8]);
        bf16x8 b = *reinterpret_cast<const bf16x8*>(wp + ks * 32);
        acc = __builtin_amdgcn_mfma_f32_16x16x32_bf16(a, b, acc, 0, 0, 0);
    }
    __syncthreads();

    int col = nt * 16 + mrow;
    if (col < N_CLASSES) {
        float bb = b2[col];
#pragma unroll
        for (int r = 0; r < 4; ++r) {
            int row = mt * 16 + kg * 4 + r;
            out_s[row][col] = acc[r] + bb;
        }
    }
    __syncthreads();

    if (tid < NB2) {
        float m = -1e30f;
        for (int j = 0; j < N_CLASSES; ++j) m = fmaxf(m, out_s[tid][j]);
        float s = 0.f;
        for (int j = 0; j < N_CLASSES; ++j) s += expf(out_s[tid][j] - m);
        lse[tid] = m + logf(s);
    }
    __syncthreads();
    for (int idx = tid; idx < NB2 * N_CLASSES; idx += 512) {
        int i = idx / N_CLASSES;
        int n = n0 + i;
        if (n < N_NODES) out[(size_t)n * N_CLASSES + (idx % N_CLASSES)] = out_s[i][idx % N_CLASSES] - lse[i];
    }
}

// ---------------- launch ----------------

extern "C" void kernel_launch(void* const* d_in, const int* in_sizes, int n_in,
                              void* d_out, int out_size, void* d_ws, size_t ws_size,
                              hipStream_t stream) {
    const float* x = (const float*)d_in[0];
    const int* ei = (const int*)d_in[1];  // int32 per harness contract
    const float* W1l = (const float*)d_in[2];
    const float* W1r = (const float*)d_in[3];
    const float* b1 = (const float*)d_in[4];
    const float* W2l = (const float*)d_in[5];
    const float* W2r = (const float*)d_in[6];
    const float* b2 = (const float*)d_in[7];
    float* out = (float*)d_out;

    char* p = (char*)d_ws;
    size_t off = 0;
    auto take = [&](size_t bytes) -> void* {
        void* r = p + off;
        off = (off + bytes + 255) & ~(size_t)255;
        return r;
    };
    int* counts = (int*)take(N_NODES * sizeof(int));
    int* row_off = (int*)take((N_NODES + 1) * sizeof(int));
    int* cursor = (int*)take(N_NODES * sizeof(int));
    float* invdeg = (float*)take(N_NODES * sizeof(float));
    int* csr_src = (int*)take(N_EDGES * sizeof(int));
    int* bsum = (int*)take((NCHUNK + 1) * sizeof(int));
    int* boff = (int*)take((NCHUNK + 1) * sizeof(int));
    unsigned short* h16 = (unsigned short*)take((size_t)N_NODES * HIDDEN * sizeof(unsigned short));
    unsigned short* Wpk1 = (unsigned short*)take(256 * 256 * sizeof(unsigned short));
    unsigned short* Wpk2 = (unsigned short*)take(64 * 512 * sizeof(unsigned short));
    unsigned short* x16 = (unsigned short*)take((size_t)N_NODES * F_IN * sizeof(unsigned short));
    // total ~= 43 MB (fit confirmed by round-7 pass with same layout)

    zero_counts<<<(N_NODES + 255) / 256, 256, 0, stream>>>(counts);
    count_kernel<<<(N_EDGES + 255) / 256, 256, 0, stream>>>(ei + N_EDGES, counts);
    scan_partials<<<NCHUNK, 256, 0, stream>>>(counts, bsum);
    scan_bsums<<<1, 256, 0, stream>>>(bsum, boff);
    scan_apply<<<NCHUNK, 256, 0, stream>>>(counts, boff, row_off, cursor, invdeg);
    fill_kernel<<<(N_EDGES + 255) / 256, 256, 0, stream>>>(ei, cursor, csr_src);
    pack_w1<<<256, 256, 0, stream>>>(W1l, W1r, Wpk1);
    pack_w2<<<64, 512, 0, stream>>>(W2l, W2r, Wpk2);
    conv_x16<<<(N_NODES * F_IN / 4 + 255) / 256, 256, 0, stream>>>(x, x16);
    gemm1_fused<<<N_NODES / 16, 256, 0, stream>>>(x16, row_off, csr_src, invdeg, Wpk1, b1, h16);
    gemm2_fused<<<(N_NODES + NB2 - 1) / NB2, 512, 0, stream>>>(h16, row_off, csr_src, invdeg,
                                                               Wpk2, b2, out);
}

// Round 9
// 265.019 us; speedup vs baseline: 1.1869x; 1.1869x over previous
//
#include <hip/hip_runtime.h>
#include <math.h>

#define N_NODES 50000
#define N_EDGES 800000
#define F_IN 128
#define HIDDEN 256
#define N_CLASSES 40

#define CHUNK 256
#define NCHUNK ((N_NODES + CHUNK - 1) / CHUNK)  // 196

typedef __attribute__((ext_vector_type(8))) short bf16x8;
typedef __attribute__((ext_vector_type(4))) float f32x4;
typedef __attribute__((ext_vector_type(8))) unsigned short u16x8;

// ---------------- bf16 helpers ----------------

__device__ __forceinline__ float bf2f(unsigned short u) {
    unsigned int t = ((unsigned int)u) << 16;
    float f;
    __builtin_memcpy(&f, &t, 4);
    return f;
}

__device__ __forceinline__ unsigned short f2bf(float f) {
    unsigned int t;
    __builtin_memcpy(&t, &f, 4);
    unsigned int r = (t + 0x7fffu + ((t >> 16) & 1u)) >> 16;  // RNE
    return (unsigned short)r;
}

// ---------------- CSR build ----------------

__global__ void zero_counts(int* __restrict__ counts) {
    int i = blockIdx.x * blockDim.x + threadIdx.x;
    if (i < N_NODES) counts[i] = 0;
}

// edge_index arrives as int32 (JAX x64-disabled downgrades int64)
__global__ void count_kernel(const int* __restrict__ dst, int* __restrict__ counts) {
    int e = blockIdx.x * blockDim.x + threadIdx.x;
    if (e < N_EDGES) {
        int d = dst[e];
        d = (d < 0) ? 0 : (d >= N_NODES ? N_NODES - 1 : d);
        atomicAdd(&counts[d], 1);
    }
}

__global__ __launch_bounds__(256) void scan_partials(const int* __restrict__ counts,
                                                     int* __restrict__ bsum) {
    __shared__ int red[4];
    int b = blockIdx.x;
    int i = b * CHUNK + threadIdx.x;
    int v = (i < N_NODES) ? counts[i] : 0;
    for (int off = 32; off > 0; off >>= 1) v += __shfl_down(v, off, 64);
    int wave = threadIdx.x >> 6;
    int lane = threadIdx.x & 63;
    if (lane == 0) red[wave] = v;
    __syncthreads();
    if (threadIdx.x == 0) bsum[b] = red[0] + red[1] + red[2] + red[3];
}

__global__ __launch_bounds__(256) void scan_bsums(int* __restrict__ bsum,
                                                  int* __restrict__ boff) {
    __shared__ int s[256];
    int tid = threadIdx.x;
    int v = (tid < NCHUNK) ? bsum[tid] : 0;
    s[tid] = v;
    __syncthreads();
    for (int off = 1; off < 256; off <<= 1) {
        int t = (tid >= off) ? s[tid - off] : 0;
        __syncthreads();
        s[tid] += t;
        __syncthreads();
    }
    if (tid < NCHUNK) boff[tid] = s[tid] - v;
    if (tid == NCHUNK - 1) boff[NCHUNK] = s[tid];
}

__global__ __launch_bounds__(256) void scan_apply(const int* __restrict__ counts,
                                                  const int* __restrict__ boff,
                                                  int* __restrict__ row_off,
                                                  int* __restrict__ cursor,
                                                  float* __restrict__ inv_deg) {
    __shared__ int s[256];
    int b = blockIdx.x;
    int tid = threadIdx.x;
    int i = b * CHUNK + tid;
    int v = (i < N_NODES) ? counts[i] : 0;
    s[tid] = v;
    __syncthreads();
    for (int off = 1; off < 256; off <<= 1) {
        int t = (tid >= off) ? s[tid - off] : 0;
        __syncthreads();
        s[tid] += t;
        __syncthreads();
    }
    if (i < N_NODES) {
        int excl = boff[b] + s[tid] - v;
        row_off[i] = excl;
        cursor[i] = excl;
        inv_deg[i] = 1.0f / fmaxf((float)v, 1.0f);
        if (i == N_NODES - 1) row_off[N_NODES] = excl + v;
    }
}

__global__ void fill_kernel(const int* __restrict__ ei, int* __restrict__ cursor,
                            int* __restrict__ csr_src) {
    int e = blockIdx.x * blockDim.x + threadIdx.x;
    if (e < N_EDGES) {
        int s = ei[e];
        int d = ei[N_EDGES + e];
        s = (s < 0) ? 0 : (s >= N_NODES ? N_NODES - 1 : s);
        d = (d < 0) ? 0 : (d >= N_NODES ? N_NODES - 1 : d);
        int pos = atomicAdd(&cursor[d], 1);
        if (pos >= 0 && pos < N_EDGES) csr_src[pos] = s;
    }
}

// ---------------- x -> bf16 conversion ----------------

__global__ void conv_x16(const float* __restrict__ x, unsigned short* __restrict__ x16) {
    int i = blockIdx.x * blockDim.x + threadIdx.x;  // 4 elems/thread
    if (i < N_NODES * F_IN / 4) {
        float4 v = reinterpret_cast<const float4*>(x)[i];
        ushort4 o;
        o.x = f2bf(v.x); o.y = f2bf(v.y); o.z = f2bf(v.z); o.w = f2bf(v.w);
        reinterpret_cast<ushort4*>(x16)[i] = o;
    }
}

// ---------------- weight packs ----------------

__global__ void pack_w1(const float* __restrict__ W1l, const float* __restrict__ W1r,
                        unsigned short* __restrict__ Wpk) {
    int n = blockIdx.x;
    int k = threadIdx.x;
    float v = (k < F_IN) ? W1l[(size_t)k * HIDDEN + n] : W1r[(size_t)(k - F_IN) * HIDDEN + n];
    Wpk[(size_t)n * 256 + k] = f2bf(v);
}

// Wpk2n[n][k] bf16, n in [0,128): n<64 -> W2l col n (0 if n>=40); n>=64 -> W2r col n-64 (0 if >=40)
__global__ void pack_w2n(const float* __restrict__ W2l, const float* __restrict__ W2r,
                         unsigned short* __restrict__ Wpk2n) {
    int n = blockIdx.x;   // 0..127
    int k = threadIdx.x;  // 0..255
    float v = 0.f;
    if (n < 64) {
        if (n < N_CLASSES) v = W2l[(size_t)k * N_CLASSES + n];
    } else {
        int m = n - 64;
        if (m < N_CLASSES) v = W2r[(size_t)k * N_CLASSES + m];
    }
    Wpk2n[(size_t)n * 256 + k] = f2bf(v);
}

// ---------------- layer 1: quarter-wave gather + MFMA + relu -> h16 ----------------
// (unchanged from round 8 -- the proven version)

#define AS1_STRIDE 264

__global__ __launch_bounds__(256) void gemm1_fused(
    const unsigned short* __restrict__ x16, const int* __restrict__ row_off,
    const int* __restrict__ csr_src, const float* __restrict__ inv_deg,
    const unsigned short* __restrict__ Wpk, const float* __restrict__ b1,
    unsigned short* __restrict__ h16) {
    __shared__ __align__(16) unsigned short As[16][AS1_STRIDE];
    int n0 = blockIdx.x * 16;
    int tid = threadIdx.x;
    int wave = tid >> 6;
    int lane = tid & 63;
    int q = lane >> 4;   // quarter 0..3
    int fl = lane & 15;  // feature lane: 8 bf16 at fl*8

    for (int j = wave; j < 16; j += 4) {
        int n = n0 + j;
        int e0 = row_off[n], e1 = row_off[n + 1];
        int deg = e1 - e0;
        float a[8] = {0.f, 0.f, 0.f, 0.f, 0.f, 0.f, 0.f, 0.f};
        int it = 0;
        for (; it + 15 < deg; it += 16) {
            int sA = csr_src[e0 + it + q];
            int sB = csr_src[e0 + it + 4 + q];
            int sC = csr_src[e0 + it + 8 + q];
            int sD = csr_src[e0 + it + 12 + q];
            u16x8 vA = *reinterpret_cast<const u16x8*>(x16 + (size_t)sA * F_IN + fl * 8);
            u16x8 vB = *reinterpret_cast<const u16x8*>(x16 + (size_t)sB * F_IN + fl * 8);
            u16x8 vC = *reinterpret_cast<const u16x8*>(x16 + (size_t)sC * F_IN + fl * 8);
            u16x8 vD = *reinterpret_cast<const u16x8*>(x16 + (size_t)sD * F_IN + fl * 8);
#pragma unroll
            for (int i = 0; i < 8; ++i)
                a[i] += (bf2f(vA[i]) + bf2f(vB[i])) + (bf2f(vC[i]) + bf2f(vD[i]));
        }
        for (; it + 3 < deg; it += 4) {
            int s = csr_src[e0 + it + q];
            u16x8 v = *reinterpret_cast<const u16x8*>(x16 + (size_t)s * F_IN + fl * 8);
#pragma unroll
            for (int i = 0; i < 8; ++i) a[i] += bf2f(v[i]);
        }
        if (it + q < deg) {
            int s = csr_src[e0 + it + q];
            u16x8 v = *reinterpret_cast<const u16x8*>(x16 + (size_t)s * F_IN + fl * 8);
#pragma unroll
            for (int i = 0; i < 8; ++i) a[i] += bf2f(v[i]);
        }
#pragma unroll
        for (int i = 0; i < 8; ++i) {
            a[i] += __shfl_xor(a[i], 16);
            a[i] += __shfl_xor(a[i], 32);
        }
        if (lane < 16) {
            float id = inv_deg[n];
            u16x8 m;
#pragma unroll
            for (int i = 0; i < 8; ++i) m[i] = f2bf(a[i] * id);
            *reinterpret_cast<u16x8*>(&As[j][fl * 8]) = m;
            *reinterpret_cast<u16x8*>(&As[j][F_IN + fl * 8]) =
                *reinterpret_cast<const u16x8*>(x16 + (size_t)n * F_IN + fl * 8);
        }
    }
    __syncthreads();

    int mrow = lane & 15;
    int kg = lane >> 4;
    f32x4 acc0 = {0.f, 0.f, 0.f, 0.f};
    f32x4 acc1 = {0.f, 0.f, 0.f, 0.f};
    f32x4 acc2 = {0.f, 0.f, 0.f, 0.f};
    f32x4 acc3 = {0.f, 0.f, 0.f, 0.f};
    const unsigned short* wp = Wpk + ((size_t)(wave * 4) * 16 + mrow) * 256 + kg * 8;
#pragma unroll
    for (int ks = 0; ks < 8; ++ks) {
        bf16x8 a = *reinterpret_cast<const bf16x8*>(&As[mrow][ks * 32 + kg * 8]);
        bf16x8 b0 = *reinterpret_cast<const bf16x8*>(wp + 0 * 16 * 256 + ks * 32);
        bf16x8 b1f = *reinterpret_cast<const bf16x8*>(wp + 1 * 16 * 256 + ks * 32);
        bf16x8 b2 = *reinterpret_cast<const bf16x8*>(wp + 2 * 16 * 256 + ks * 32);
        bf16x8 b3 = *reinterpret_cast<const bf16x8*>(wp + 3 * 16 * 256 + ks * 32);
        acc0 = __builtin_amdgcn_mfma_f32_16x16x32_bf16(a, b0, acc0, 0, 0, 0);
        acc1 = __builtin_amdgcn_mfma_f32_16x16x32_bf16(a, b1f, acc1, 0, 0, 0);
        acc2 = __builtin_amdgcn_mfma_f32_16x16x32_bf16(a, b2, acc2, 0, 0, 0);
        acc3 = __builtin_amdgcn_mfma_f32_16x16x32_bf16(a, b3, acc3, 0, 0, 0);
    }
    f32x4 accs[4] = {acc0, acc1, acc2, acc3};
#pragma unroll
    for (int i = 0; i < 4; ++i) {
        int n = (wave * 4 + i) * 16 + mrow;
        float bb = b1[n];
#pragma unroll
        for (int r = 0; r < 4; ++r) {
            int row = kg * 4 + r;
            h16[(size_t)(n0 + row) * HIDDEN + n] = f2bf(fmaxf(accs[i][r] + bb, 0.f));
        }
    }
}

// ---------------- proj2: hWl = h@W2l (bf16 [n][64]), hWr = h@W2r + b2 (bf16 [n][48]) ----------
// 256 threads (4 waves), 16 rows/block. Pure streaming + MFMA (no gather).

__global__ __launch_bounds__(256) void proj2(
    const unsigned short* __restrict__ h16, const unsigned short* __restrict__ Wpk2n,
    const float* __restrict__ b2, unsigned short* __restrict__ hWl,
    unsigned short* __restrict__ hWr) {
    __shared__ __align__(16) unsigned short As[16][AS1_STRIDE];
    int n0 = blockIdx.x * 16;
    int tid = threadIdx.x;
    int wave = tid >> 6;
    int lane = tid & 63;

    // stage 16x256 bf16 tile, coalesced
#pragma unroll
    for (int itn = 0; itn < 2; ++itn) {
        int u = itn * 256 + tid;     // u16x8 unit id, 512 total
        int row = u >> 5;            // /32
        int col = (u & 31) * 8;
        *reinterpret_cast<u16x8*>(&As[row][col]) =
            *reinterpret_cast<const u16x8*>(h16 + (size_t)(n0 + row) * HIDDEN + col);
    }
    __syncthreads();

    int mrow = lane & 15;
    int kg = lane >> 4;
    // wave handles tiles t = wave (hWl cols) and t = wave+4 (hWr cols)
    f32x4 accL = {0.f, 0.f, 0.f, 0.f};
    f32x4 accR = {0.f, 0.f, 0.f, 0.f};
    const unsigned short* wpL = Wpk2n + ((size_t)(wave * 16 + mrow)) * 256 + kg * 8;
    const unsigned short* wpR = Wpk2n + ((size_t)((wave + 4) * 16 + mrow)) * 256 + kg * 8;
#pragma unroll
    for (int ks = 0; ks < 8; ++ks) {
        bf16x8 a = *reinterpret_cast<const bf16x8*>(&As[mrow][ks * 32 + kg * 8]);
        bf16x8 bL = *reinterpret_cast<const bf16x8*>(wpL + ks * 32);
        bf16x8 bR = *reinterpret_cast<const bf16x8*>(wpR + ks * 32);
        accL = __builtin_amdgcn_mfma_f32_16x16x32_bf16(a, bL, accL, 0, 0, 0);
        accR = __builtin_amdgcn_mfma_f32_16x16x32_bf16(a, bR, accR, 0, 0, 0);
    }
    int colL = wave * 16 + mrow;  // 0..63
    int colR = wave * 16 + mrow;  // 0..63 (only <48 stored)
    float bb = (colR < N_CLASSES) ? b2[colR] : 0.f;
#pragma unroll
    for (int r = 0; r < 4; ++r) {
        int row = kg * 4 + r;
        hWl[(size_t)(n0 + row) * 64 + colL] = f2bf(accL[r]);
        if (colR < 48) hWr[(size_t)(n0 + row) * 48 + colR] = f2bf(accR[r] + bb);
    }
}

// ---------------- k2b: gather-mean of hWl + hWr[dst] + log_softmax ----------------
// 256 threads (4 waves), 16 nodes/block, no LDS. Quarter-wave (16 lanes x 8B) per edge:
// 4 edges parallel per wave, x4 unroll = 16 edges (4x8B loads/lane) in flight.

__global__ __launch_bounds__(256) void k2b(
    const unsigned short* __restrict__ hWl, const unsigned short* __restrict__ hWr,
    const int* __restrict__ row_off, const int* __restrict__ csr_src,
    const float* __restrict__ inv_deg, float* __restrict__ out) {
    int n0 = blockIdx.x * 16;
    int tid = threadIdx.x;
    int wave = tid >> 6;
    int lane = tid & 63;
    int q = lane >> 4;   // quarter 0..3
    int fl = lane & 15;  // covers cols fl*4 .. fl*4+3

    for (int j = wave; j < 16; j += 4) {
        int n = n0 + j;
        int e0 = row_off[n], e1 = row_off[n + 1];
        int deg = e1 - e0;
        float a0 = 0.f, a1 = 0.f, a2 = 0.f, a3 = 0.f;
        int it = 0;
        for (; it + 15 < deg; it += 16) {
            int sA = csr_src[e0 + it + q];
            int sB = csr_src[e0 + it + 4 + q];
            int sC = csr_src[e0 + it + 8 + q];
            int sD = csr_src[e0 + it + 12 + q];
            ushort4 vA = *reinterpret_cast<const ushort4*>(hWl + (size_t)sA * 64 + fl * 4);
            ushort4 vB = *reinterpret_cast<const ushort4*>(hWl + (size_t)sB * 64 + fl * 4);
            ushort4 vC = *reinterpret_cast<const ushort4*>(hWl + (size_t)sC * 64 + fl * 4);
            ushort4 vD = *reinterpret_cast<const ushort4*>(hWl + (size_t)sD * 64 + fl * 4);
            a0 += (bf2f(vA.x) + bf2f(vB.x)) + (bf2f(vC.x) + bf2f(vD.x));
            a1 += (bf2f(vA.y) + bf2f(vB.y)) + (bf2f(vC.y) + bf2f(vD.y));
            a2 += (bf2f(vA.z) + bf2f(vB.z)) + (bf2f(vC.z) + bf2f(vD.z));
            a3 += (bf2f(vA.w) + bf2f(vB.w)) + (bf2f(vC.w) + bf2f(vD.w));
        }
        for (; it + 3 < deg; it += 4) {
            int s = csr_src[e0 + it + q];
            ushort4 v = *reinterpret_cast<const ushort4*>(hWl + (size_t)s * 64 + fl * 4);
            a0 += bf2f(v.x); a1 += bf2f(v.y); a2 += bf2f(v.z); a3 += bf2f(v.w);
        }
        if (it + q < deg) {
            int s = csr_src[e0 + it + q];
            ushort4 v = *reinterpret_cast<const ushort4*>(hWl + (size_t)s * 64 + fl * 4);
            a0 += bf2f(v.x); a1 += bf2f(v.y); a2 += bf2f(v.z); a3 += bf2f(v.w);
        }
        a0 += __shfl_xor(a0, 16); a0 += __shfl_xor(a0, 32);
        a1 += __shfl_xor(a1, 16); a1 += __shfl_xor(a1, 32);
        a2 += __shfl_xor(a2, 16); a2 += __shfl_xor(a2, 32);
        a3 += __shfl_xor(a3, 16); a3 += __shfl_xor(a3, 32);

        // lanes 0..15 now hold full sums; do LSM within the first quarter
        float v0 = 0.f, v1 = 0.f, v2 = 0.f, v3 = 0.f;
        bool valid = (lane < 16) && (fl < 10);  // cols fl*4..fl*4+3 < 40
        if (valid) {
            float id = inv_deg[n];
            ushort4 r = *reinterpret_cast<const ushort4*>(hWr + (size_t)n * 48 + fl * 4);
            v0 = a0 * id + bf2f(r.x);
            v1 = a1 * id + bf2f(r.y);
            v2 = a2 * id + bf2f(r.z);
            v3 = a3 * id + bf2f(r.w);
        }
        float m = valid ? fmaxf(fmaxf(v0, v1), fmaxf(v2, v3)) : -1e30f;
        m = fmaxf(m, __shfl_xor(m, 1));
        m = fmaxf(m, __shfl_xor(m, 2));
        m = fmaxf(m, __shfl_xor(m, 4));
        m = fmaxf(m, __shfl_xor(m, 8));
        float s = valid ? (expf(v0 - m) + expf(v1 - m)) + (expf(v2 - m) + expf(v3 - m)) : 0.f;
        s += __shfl_xor(s, 1);
        s += __shfl_xor(s, 2);
        s += __shfl_xor(s, 4);
        s += __shfl_xor(s, 8);
        float lse = m + logf(s);
        if (valid) {
            float4 o;
            o.x = v0 - lse; o.y = v1 - lse; o.z = v2 - lse; o.w = v3 - lse;
            *reinterpret_cast<float4*>(out + (size_t)n * N_CLASSES + fl * 4) = o;
        }
    }
}

// ---------------- launch ----------------

extern "C" void kernel_launch(void* const* d_in, const int* in_sizes, int n_in,
                              void* d_out, int out_size, void* d_ws, size_t ws_size,
                              hipStream_t stream) {
    const float* x = (const float*)d_in[0];
    const int* ei = (const int*)d_in[1];  // int32 per harness contract
    const float* W1l = (const float*)d_in[2];
    const float* W1r = (const float*)d_in[3];
    const float* b1 = (const float*)d_in[4];
    const float* W2l = (const float*)d_in[5];
    const float* W2r = (const float*)d_in[6];
    const float* b2 = (const float*)d_in[7];
    float* out = (float*)d_out;

    char* p = (char*)d_ws;
    size_t off = 0;
    auto take = [&](size_t bytes) -> void* {
        void* r = p + off;
        off = (off + bytes + 255) & ~(size_t)255;
        return r;
    };
    int* counts = (int*)take(N_NODES * sizeof(int));
    int* row_off = (int*)take((N_NODES + 1) * sizeof(int));
    int* cursor = (int*)take(N_NODES * sizeof(int));
    float* invdeg = (float*)take(N_NODES * sizeof(float));
    int* csr_src = (int*)take(N_EDGES * sizeof(int));
    int* bsum = (int*)take((NCHUNK + 1) * sizeof(int));
    int* boff = (int*)take((NCHUNK + 1) * sizeof(int));
    unsigned short* h16 = (unsigned short*)take((size_t)N_NODES * HIDDEN * sizeof(unsigned short));
    unsigned short* Wpk1 = (unsigned short*)take(256 * 256 * sizeof(unsigned short));
    unsigned short* Wpk2n = (unsigned short*)take(128 * 256 * sizeof(unsigned short));
    unsigned short* x16 = (unsigned short*)take((size_t)N_NODES * F_IN * sizeof(unsigned short));
    // x16 (12.8 MB) is dead after gemm1; hWl (6.4 MB) + hWr (4.8 MB) reuse its space.
    unsigned short* hWl = x16;
    unsigned short* hWr = x16 + (size_t)N_NODES * 64;
    // total unchanged from round 7/8 (~43 MB, proven to fit)

    zero_counts<<<(N_NODES + 255) / 256, 256, 0, stream>>>(counts);
    count_kernel<<<(N_EDGES + 255) / 256, 256, 0, stream>>>(ei + N_EDGES, counts);
    scan_partials<<<NCHUNK, 256, 0, stream>>>(counts, bsum);
    scan_bsums<<<1, 256, 0, stream>>>(bsum, boff);
    scan_apply<<<NCHUNK, 256, 0, stream>>>(counts, boff, row_off, cursor, invdeg);
    fill_kernel<<<(N_EDGES + 255) / 256, 256, 0, stream>>>(ei, cursor, csr_src);
    pack_w1<<<256, 256, 0, stream>>>(W1l, W1r, Wpk1);
    pack_w2n<<<128, 256, 0, stream>>>(W2l, W2r, Wpk2n);
    conv_x16<<<(N_NODES * F_IN / 4 + 255) / 256, 256, 0, stream>>>(x, x16);
    gemm1_fused<<<N_NODES / 16, 256, 0, stream>>>(x16, row_off, csr_src, invdeg, Wpk1, b1, h16);
    proj2<<<N_NODES / 16, 256, 0, stream>>>(h16, Wpk2n, b2, hWl, hWr);
    k2b<<<N_NODES / 16, 256, 0, stream>>>(hWl, hWr, row_off, csr_src, invdeg, out);
}

// Round 10
// 232.078 us; speedup vs baseline: 1.3554x; 1.1419x over previous
//
#include <hip/hip_runtime.h>
#include <math.h>

#define N_NODES 50000
#define N_EDGES 800000
#define F_IN 128
#define HIDDEN 256
#define N_CLASSES 40

#define CHUNK 256
#define NCHUNK ((N_NODES + CHUNK - 1) / CHUNK)  // 196

typedef __attribute__((ext_vector_type(8))) short bf16x8;
typedef __attribute__((ext_vector_type(4))) float f32x4;
typedef __attribute__((ext_vector_type(8))) unsigned short u16x8;

// ---------------- bf16 helpers ----------------

__device__ __forceinline__ float bf2f(unsigned short u) {
    unsigned int t = ((unsigned int)u) << 16;
    float f;
    __builtin_memcpy(&f, &t, 4);
    return f;
}

__device__ __forceinline__ unsigned short f2bf(float f) {
    unsigned int t;
    __builtin_memcpy(&t, &f, 4);
    unsigned int r = (t + 0x7fffu + ((t >> 16) & 1u)) >> 16;  // RNE
    return (unsigned short)r;
}

// ---------------- CSR build ----------------

__global__ void zero_counts(int* __restrict__ counts) {
    int i = blockIdx.x * blockDim.x + threadIdx.x;
    if (i < N_NODES) counts[i] = 0;
}

// edge_index arrives as int32 (JAX x64-disabled downgrades int64)
__global__ void count_kernel(const int* __restrict__ dst, int* __restrict__ counts) {
    int e = blockIdx.x * blockDim.x + threadIdx.x;
    if (e < N_EDGES) {
        int d = dst[e];
        d = (d < 0) ? 0 : (d >= N_NODES ? N_NODES - 1 : d);
        atomicAdd(&counts[d], 1);
    }
}

__global__ __launch_bounds__(256) void scan_partials(const int* __restrict__ counts,
                                                     int* __restrict__ bsum) {
    __shared__ int red[4];
    int b = blockIdx.x;
    int i = b * CHUNK + threadIdx.x;
    int v = (i < N_NODES) ? counts[i] : 0;
    for (int off = 32; off > 0; off >>= 1) v += __shfl_down(v, off, 64);
    int wave = threadIdx.x >> 6;
    int lane = threadIdx.x & 63;
    if (lane == 0) red[wave] = v;
    __syncthreads();
    if (threadIdx.x == 0) bsum[b] = red[0] + red[1] + red[2] + red[3];
}

__global__ __launch_bounds__(256) void scan_bsums(int* __restrict__ bsum,
                                                  int* __restrict__ boff) {
    __shared__ int s[256];
    int tid = threadIdx.x;
    int v = (tid < NCHUNK) ? bsum[tid] : 0;
    s[tid] = v;
    __syncthreads();
    for (int off = 1; off < 256; off <<= 1) {
        int t = (tid >= off) ? s[tid - off] : 0;
        __syncthreads();
        s[tid] += t;
        __syncthreads();
    }
    if (tid < NCHUNK) boff[tid] = s[tid] - v;
    if (tid == NCHUNK - 1) boff[NCHUNK] = s[tid];
}

__global__ __launch_bounds__(256) void scan_apply(const int* __restrict__ counts,
                                                  const int* __restrict__ boff,
                                                  int* __restrict__ row_off,
                                                  int* __restrict__ cursor,
                                                  float* __restrict__ inv_deg) {
    __shared__ int s[256];
    int b = blockIdx.x;
    int tid = threadIdx.x;
    int i = b * CHUNK + tid;
    int v = (i < N_NODES) ? counts[i] : 0;
    s[tid] = v;
    __syncthreads();
    for (int off = 1; off < 256; off <<= 1) {
        int t = (tid >= off) ? s[tid - off] : 0;
        __syncthreads();
        s[tid] += t;
        __syncthreads();
    }
    if (i < N_NODES) {
        int excl = boff[b] + s[tid] - v;
        row_off[i] = excl;
        cursor[i] = excl;
        inv_deg[i] = 1.0f / fmaxf((float)v, 1.0f);
        if (i == N_NODES - 1) row_off[N_NODES] = excl + v;
    }
}

__global__ void fill_kernel(const int* __restrict__ ei, int* __restrict__ cursor,
                            int* __restrict__ csr_src) {
    int e = blockIdx.x * blockDim.x + threadIdx.x;
    if (e < N_EDGES) {
        int s = ei[e];
        int d = ei[N_EDGES + e];
        s = (s < 0) ? 0 : (s >= N_NODES ? N_NODES - 1 : s);
        d = (d < 0) ? 0 : (d >= N_NODES ? N_NODES - 1 : d);
        int pos = atomicAdd(&cursor[d], 1);
        if (pos >= 0 && pos < N_EDGES) csr_src[pos] = s;
    }
}

// ---------------- x -> bf16 conversion ----------------

__global__ void conv_x16(const float* __restrict__ x, unsigned short* __restrict__ x16) {
    int i = blockIdx.x * blockDim.x + threadIdx.x;  // 4 elems/thread
    if (i < N_NODES * F_IN / 4) {
        float4 v = reinterpret_cast<const float4*>(x)[i];
        ushort4 o;
        o.x = f2bf(v.x); o.y = f2bf(v.y); o.z = f2bf(v.z); o.w = f2bf(v.w);
        reinterpret_cast<ushort4*>(x16)[i] = o;
    }
}

// ---------------- weight packs ----------------

__global__ void pack_w1(const float* __restrict__ W1l, const float* __restrict__ W1r,
                        unsigned short* __restrict__ Wpk) {
    int n = blockIdx.x;
    int k = threadIdx.x;
    float v = (k < F_IN) ? W1l[(size_t)k * HIDDEN + n] : W1r[(size_t)(k - F_IN) * HIDDEN + n];
    Wpk[(size_t)n * 256 + k] = f2bf(v);
}

// Wpk2n[n][k] bf16, n in [0,128): n<64 -> W2l col n (0 if n>=40); n>=64 -> W2r col n-64 (0 if >=40)
__global__ void pack_w2n(const float* __restrict__ W2l, const float* __restrict__ W2r,
                         unsigned short* __restrict__ Wpk2n) {
    int n = blockIdx.x;   // 0..127
    int k = threadIdx.x;  // 0..255
    float v = 0.f;
    if (n < 64) {
        if (n < N_CLASSES) v = W2l[(size_t)k * N_CLASSES + n];
    } else {
        int m = n - 64;
        if (m < N_CLASSES) v = W2r[(size_t)k * N_CLASSES + m];
    }
    Wpk2n[(size_t)n * 256 + k] = f2bf(v);
}

// ---------------- layer 1: quarter-per-node gather + MFMA + relu -> h16 ----------------
// 256 threads (4 waves), 16 nodes/block. Quarter-wave OWNS one node (j = tid>>4):
// all 16 nodes gather in parallel; unroll 8 = 8x16B loads in flight per lane; no shuffles.

#define AS1_STRIDE 264

__global__ __launch_bounds__(256) void gemm1_fused(
    const unsigned short* __restrict__ x16, const int* __restrict__ row_off,
    const int* __restrict__ csr_src, const float* __restrict__ inv_deg,
    const unsigned short* __restrict__ Wpk, const float* __restrict__ b1,
    unsigned short* __restrict__ h16) {
    __shared__ __align__(16) unsigned short As[16][AS1_STRIDE];
    int n0 = blockIdx.x * 16;
    int tid = threadIdx.x;
    int wave = tid >> 6;
    int lane = tid & 63;
    int j = tid >> 4;    // node 0..15, one quarter-wave each
    int fl = tid & 15;   // feature lane: 8 bf16 at fl*8

    {
        int n = n0 + j;
        int e0 = row_off[n], e1 = row_off[n + 1];
        int deg = e1 - e0;
        float a[8] = {0.f, 0.f, 0.f, 0.f, 0.f, 0.f, 0.f, 0.f};
        int it = 0;
        for (; it + 7 < deg; it += 8) {  // 8 rows in flight per lane
            int s0 = csr_src[e0 + it + 0];
            int s1 = csr_src[e0 + it + 1];
            int s2 = csr_src[e0 + it + 2];
            int s3 = csr_src[e0 + it + 3];
            int s4 = csr_src[e0 + it + 4];
            int s5 = csr_src[e0 + it + 5];
            int s6 = csr_src[e0 + it + 6];
            int s7 = csr_src[e0 + it + 7];
            u16x8 v0 = *reinterpret_cast<const u16x8*>(x16 + (size_t)s0 * F_IN + fl * 8);
            u16x8 v1 = *reinterpret_cast<const u16x8*>(x16 + (size_t)s1 * F_IN + fl * 8);
            u16x8 v2 = *reinterpret_cast<const u16x8*>(x16 + (size_t)s2 * F_IN + fl * 8);
            u16x8 v3 = *reinterpret_cast<const u16x8*>(x16 + (size_t)s3 * F_IN + fl * 8);
            u16x8 v4 = *reinterpret_cast<const u16x8*>(x16 + (size_t)s4 * F_IN + fl * 8);
            u16x8 v5 = *reinterpret_cast<const u16x8*>(x16 + (size_t)s5 * F_IN + fl * 8);
            u16x8 v6 = *reinterpret_cast<const u16x8*>(x16 + (size_t)s6 * F_IN + fl * 8);
            u16x8 v7 = *reinterpret_cast<const u16x8*>(x16 + (size_t)s7 * F_IN + fl * 8);
#pragma unroll
            for (int i = 0; i < 8; ++i)
                a[i] += ((bf2f(v0[i]) + bf2f(v1[i])) + (bf2f(v2[i]) + bf2f(v3[i]))) +
                        ((bf2f(v4[i]) + bf2f(v5[i])) + (bf2f(v6[i]) + bf2f(v7[i])));
        }
        if (it + 3 < deg) {  // 4 rows
            int s0 = csr_src[e0 + it + 0];
            int s1 = csr_src[e0 + it + 1];
            int s2 = csr_src[e0 + it + 2];
            int s3 = csr_src[e0 + it + 3];
            u16x8 v0 = *reinterpret_cast<const u16x8*>(x16 + (size_t)s0 * F_IN + fl * 8);
            u16x8 v1 = *reinterpret_cast<const u16x8*>(x16 + (size_t)s1 * F_IN + fl * 8);
            u16x8 v2 = *reinterpret_cast<const u16x8*>(x16 + (size_t)s2 * F_IN + fl * 8);
            u16x8 v3 = *reinterpret_cast<const u16x8*>(x16 + (size_t)s3 * F_IN + fl * 8);
#pragma unroll
            for (int i = 0; i < 8; ++i)
                a[i] += (bf2f(v0[i]) + bf2f(v1[i])) + (bf2f(v2[i]) + bf2f(v3[i]));
            it += 4;
        }
        for (; it < deg; ++it) {  // up to 3 singles
            int s = csr_src[e0 + it];
            u16x8 v = *reinterpret_cast<const u16x8*>(x16 + (size_t)s * F_IN + fl * 8);
#pragma unroll
            for (int i = 0; i < 8; ++i) a[i] += bf2f(v[i]);
        }
        float id = inv_deg[n];
        u16x8 m;
#pragma unroll
        for (int i = 0; i < 8; ++i) m[i] = f2bf(a[i] * id);
        *reinterpret_cast<u16x8*>(&As[j][fl * 8]) = m;
        *reinterpret_cast<u16x8*>(&As[j][F_IN + fl * 8]) =
            *reinterpret_cast<const u16x8*>(x16 + (size_t)n * F_IN + fl * 8);
    }
    __syncthreads();

    // ---- MFMA phase (m89-verified layout, unchanged) ----
    int mrow = lane & 15;
    int kg = lane >> 4;
    f32x4 acc0 = {0.f, 0.f, 0.f, 0.f};
    f32x4 acc1 = {0.f, 0.f, 0.f, 0.f};
    f32x4 acc2 = {0.f, 0.f, 0.f, 0.f};
    f32x4 acc3 = {0.f, 0.f, 0.f, 0.f};
    const unsigned short* wp = Wpk + ((size_t)(wave * 4) * 16 + mrow) * 256 + kg * 8;
#pragma unroll
    for (int ks = 0; ks < 8; ++ks) {
        bf16x8 a = *reinterpret_cast<const bf16x8*>(&As[mrow][ks * 32 + kg * 8]);
        bf16x8 b0 = *reinterpret_cast<const bf16x8*>(wp + 0 * 16 * 256 + ks * 32);
        bf16x8 b1f = *reinterpret_cast<const bf16x8*>(wp + 1 * 16 * 256 + ks * 32);
        bf16x8 b2 = *reinterpret_cast<const bf16x8*>(wp + 2 * 16 * 256 + ks * 32);
        bf16x8 b3 = *reinterpret_cast<const bf16x8*>(wp + 3 * 16 * 256 + ks * 32);
        acc0 = __builtin_amdgcn_mfma_f32_16x16x32_bf16(a, b0, acc0, 0, 0, 0);
        acc1 = __builtin_amdgcn_mfma_f32_16x16x32_bf16(a, b1f, acc1, 0, 0, 0);
        acc2 = __builtin_amdgcn_mfma_f32_16x16x32_bf16(a, b2, acc2, 0, 0, 0);
        acc3 = __builtin_amdgcn_mfma_f32_16x16x32_bf16(a, b3, acc3, 0, 0, 0);
    }
    f32x4 accs[4] = {acc0, acc1, acc2, acc3};
#pragma unroll
    for (int i = 0; i < 4; ++i) {
        int n = (wave * 4 + i) * 16 + mrow;
        float bb = b1[n];
#pragma unroll
        for (int r = 0; r < 4; ++r) {
            int row = kg * 4 + r;
            h16[(size_t)(n0 + row) * HIDDEN + n] = f2bf(fmaxf(accs[i][r] + bb, 0.f));
        }
    }
}

// ---------------- proj2: hWl = h@W2l (bf16 [n][64]), hWr = h@W2r + b2 (bf16 [n][48]) ----------

__global__ __launch_bounds__(256) void proj2(
    const unsigned short* __restrict__ h16, const unsigned short* __restrict__ Wpk2n,
    const float* __restrict__ b2, unsigned short* __restrict__ hWl,
    unsigned short* __restrict__ hWr) {
    __shared__ __align__(16) unsigned short As[16][AS1_STRIDE];
    int n0 = blockIdx.x * 16;
    int tid = threadIdx.x;
    int wave = tid >> 6;
    int lane = tid & 63;

#pragma unroll
    for (int itn = 0; itn < 2; ++itn) {
        int u = itn * 256 + tid;
        int row = u >> 5;
        int col = (u & 31) * 8;
        *reinterpret_cast<u16x8*>(&As[row][col]) =
            *reinterpret_cast<const u16x8*>(h16 + (size_t)(n0 + row) * HIDDEN + col);
    }
    __syncthreads();

    int mrow = lane & 15;
    int kg = lane >> 4;
    f32x4 accL = {0.f, 0.f, 0.f, 0.f};
    f32x4 accR = {0.f, 0.f, 0.f, 0.f};
    const unsigned short* wpL = Wpk2n + ((size_t)(wave * 16 + mrow)) * 256 + kg * 8;
    const unsigned short* wpR = Wpk2n + ((size_t)((wave + 4) * 16 + mrow)) * 256 + kg * 8;
#pragma unroll
    for (int ks = 0; ks < 8; ++ks) {
        bf16x8 a = *reinterpret_cast<const bf16x8*>(&As[mrow][ks * 32 + kg * 8]);
        bf16x8 bL = *reinterpret_cast<const bf16x8*>(wpL + ks * 32);
        bf16x8 bR = *reinterpret_cast<const bf16x8*>(wpR + ks * 32);
        accL = __builtin_amdgcn_mfma_f32_16x16x32_bf16(a, bL, accL, 0, 0, 0);
        accR = __builtin_amdgcn_mfma_f32_16x16x32_bf16(a, bR, accR, 0, 0, 0);
    }
    int colL = wave * 16 + mrow;
    int colR = wave * 16 + mrow;
    float bb = (colR < N_CLASSES) ? b2[colR] : 0.f;
#pragma unroll
    for (int r = 0; r < 4; ++r) {
        int row = kg * 4 + r;
        hWl[(size_t)(n0 + row) * 64 + colL] = f2bf(accL[r]);
        if (colR < 48) hWr[(size_t)(n0 + row) * 48 + colR] = f2bf(accR[r] + bb);
    }
}

// ---------------- k2b: quarter-per-node gather of hWl + hWr[dst] + log_softmax ----------------
// 256 threads, 16 nodes/block, no LDS. Quarter-wave owns node j = tid>>4; lane covers 4 cols.
// Unroll 8 = 8x8B loads in flight per lane.

__global__ __launch_bounds__(256) void k2b(
    const unsigned short* __restrict__ hWl, const unsigned short* __restrict__ hWr,
    const int* __restrict__ row_off, const int* __restrict__ csr_src,
    const float* __restrict__ inv_deg, float* __restrict__ out) {
    int n0 = blockIdx.x * 16;
    int tid = threadIdx.x;
    int j = tid >> 4;    // node 0..15
    int fl = tid & 15;   // cols fl*4 .. fl*4+3

    int n = n0 + j;
    int e0 = row_off[n], e1 = row_off[n + 1];
    int deg = e1 - e0;
    float a0 = 0.f, a1 = 0.f, a2 = 0.f, a3 = 0.f;
    int it = 0;
    for (; it + 7 < deg; it += 8) {
        int s0 = csr_src[e0 + it + 0];
        int s1 = csr_src[e0 + it + 1];
        int s2 = csr_src[e0 + it + 2];
        int s3 = csr_src[e0 + it + 3];
        int s4 = csr_src[e0 + it + 4];
        int s5 = csr_src[e0 + it + 5];
        int s6 = csr_src[e0 + it + 6];
        int s7 = csr_src[e0 + it + 7];
        ushort4 v0 = *reinterpret_cast<const ushort4*>(hWl + (size_t)s0 * 64 + fl * 4);
        ushort4 v1 = *reinterpret_cast<const ushort4*>(hWl + (size_t)s1 * 64 + fl * 4);
        ushort4 v2 = *reinterpret_cast<const ushort4*>(hWl + (size_t)s2 * 64 + fl * 4);
        ushort4 v3 = *reinterpret_cast<const ushort4*>(hWl + (size_t)s3 * 64 + fl * 4);
        ushort4 v4 = *reinterpret_cast<const ushort4*>(hWl + (size_t)s4 * 64 + fl * 4);
        ushort4 v5 = *reinterpret_cast<const ushort4*>(hWl + (size_t)s5 * 64 + fl * 4);
        ushort4 v6 = *reinterpret_cast<const ushort4*>(hWl + (size_t)s6 * 64 + fl * 4);
        ushort4 v7 = *reinterpret_cast<const ushort4*>(hWl + (size_t)s7 * 64 + fl * 4);
        a0 += ((bf2f(v0.x) + bf2f(v1.x)) + (bf2f(v2.x) + bf2f(v3.x))) +
              ((bf2f(v4.x) + bf2f(v5.x)) + (bf2f(v6.x) + bf2f(v7.x)));
        a1 += ((bf2f(v0.y) + bf2f(v1.y)) + (bf2f(v2.y) + bf2f(v3.y))) +
              ((bf2f(v4.y) + bf2f(v5.y)) + (bf2f(v6.y) + bf2f(v7.y)));
        a2 += ((bf2f(v0.z) + bf2f(v1.z)) + (bf2f(v2.z) + bf2f(v3.z))) +
              ((bf2f(v4.z) + bf2f(v5.z)) + (bf2f(v6.z) + bf2f(v7.z)));
        a3 += ((bf2f(v0.w) + bf2f(v1.w)) + (bf2f(v2.w) + bf2f(v3.w))) +
              ((bf2f(v4.w) + bf2f(v5.w)) + (bf2f(v6.w) + bf2f(v7.w)));
    }
    if (it + 3 < deg) {
        int s0 = csr_src[e0 + it + 0];
        int s1 = csr_src[e0 + it + 1];
        int s2 = csr_src[e0 + it + 2];
        int s3 = csr_src[e0 + it + 3];
        ushort4 v0 = *reinterpret_cast<const ushort4*>(hWl + (size_t)s0 * 64 + fl * 4);
        ushort4 v1 = *reinterpret_cast<const ushort4*>(hWl + (size_t)s1 * 64 + fl * 4);
        ushort4 v2 = *reinterpret_cast<const ushort4*>(hWl + (size_t)s2 * 64 + fl * 4);
        ushort4 v3 = *reinterpret_cast<const ushort4*>(hWl + (size_t)s3 * 64 + fl * 4);
        a0 += (bf2f(v0.x) + bf2f(v1.x)) + (bf2f(v2.x) + bf2f(v3.x));
        a1 += (bf2f(v0.y) + bf2f(v1.y)) + (bf2f(v2.y) + bf2f(v3.y));
        a2 += (bf2f(v0.z) + bf2f(v1.z)) + (bf2f(v2.z) + bf2f(v3.z));
        a3 += (bf2f(v0.w) + bf2f(v1.w)) + (bf2f(v2.w) + bf2f(v3.w));
        it += 4;
    }
    for (; it < deg; ++it) {
        int s = csr_src[e0 + it];
        ushort4 v = *reinterpret_cast<const ushort4*>(hWl + (size_t)s * 64 + fl * 4);
        a0 += bf2f(v.x); a1 += bf2f(v.y); a2 += bf2f(v.z); a3 += bf2f(v.w);
    }

    float v0 = 0.f, v1 = 0.f, v2 = 0.f, v3 = 0.f;
    bool valid = (fl < 10);  // cols fl*4..fl*4+3 < 40
    if (valid) {
        float id = inv_deg[n];
        ushort4 r = *reinterpret_cast<const ushort4*>(hWr + (size_t)n * 48 + fl * 4);
        v0 = a0 * id + bf2f(r.x);
        v1 = a1 * id + bf2f(r.y);
        v2 = a2 * id + bf2f(r.z);
        v3 = a3 * id + bf2f(r.w);
    }
    float m = valid ? fmaxf(fmaxf(v0, v1), fmaxf(v2, v3)) : -1e30f;
    m = fmaxf(m, __shfl_xor(m, 1));
    m = fmaxf(m, __shfl_xor(m, 2));
    m = fmaxf(m, __shfl_xor(m, 4));
    m = fmaxf(m, __shfl_xor(m, 8));
    float s = valid ? (expf(v0 - m) + expf(v1 - m)) + (expf(v2 - m) + expf(v3 - m)) : 0.f;
    s += __shfl_xor(s, 1);
    s += __shfl_xor(s, 2);
    s += __shfl_xor(s, 4);
    s += __shfl_xor(s, 8);
    float lse = m + logf(s);
    if (valid) {
        float4 o;
        o.x = v0 - lse; o.y = v1 - lse; o.z = v2 - lse; o.w = v3 - lse;
        *reinterpret_cast<float4*>(out + (size_t)n * N_CLASSES + fl * 4) = o;
    }
}

// ---------------- launch ----------------

extern "C" void kernel_launch(void* const* d_in, const int* in_sizes, int n_in,
                              void* d_out, int out_size, void* d_ws, size_t ws_size,
                              hipStream_t stream) {
    const float* x = (const float*)d_in[0];
    const int* ei = (const int*)d_in[1];  // int32 per harness contract
    const float* W1l = (const float*)d_in[2];
    const float* W1r = (const float*)d_in[3];
    const float* b1 = (const float*)d_in[4];
    const float* W2l = (const float*)d_in[5];
    const float* W2r = (const float*)d_in[6];
    const float* b2 = (const float*)d_in[7];
    float* out = (float*)d_out;

    char* p = (char*)d_ws;
    size_t off = 0;
    auto take = [&](size_t bytes) -> void* {
        void* r = p + off;
        off = (off + bytes + 255) & ~(size_t)255;
        return r;
    };
    int* counts = (int*)take(N_NODES * sizeof(int));
    int* row_off = (int*)take((N_NODES + 1) * sizeof(int));
    int* cursor = (int*)take(N_NODES * sizeof(int));
    float* invdeg = (float*)take(N_NODES * sizeof(float));
    int* csr_src = (int*)take(N_EDGES * sizeof(int));
    int* bsum = (int*)take((NCHUNK + 1) * sizeof(int));
    int* boff = (int*)take((NCHUNK + 1) * sizeof(int));
    unsigned short* h16 = (unsigned short*)take((size_t)N_NODES * HIDDEN * sizeof(unsigned short));
    unsigned short* Wpk1 = (unsigned short*)take(256 * 256 * sizeof(unsigned short));
    unsigned short* Wpk2n = (unsigned short*)take(128 * 256 * sizeof(unsigned short));
    unsigned short* x16 = (unsigned short*)take((size_t)N_NODES * F_IN * sizeof(unsigned short));
    // x16 (12.8 MB) is dead after gemm1; hWl (6.4 MB) + hWr (4.8 MB) reuse its space.
    unsigned short* hWl = x16;
    unsigned short* hWr = x16 + (size_t)N_NODES * 64;

    zero_counts<<<(N_NODES + 255) / 256, 256, 0, stream>>>(counts);
    count_kernel<<<(N_EDGES + 255) / 256, 256, 0, stream>>>(ei + N_EDGES, counts);
    scan_partials<<<NCHUNK, 256, 0, stream>>>(counts, bsum);
    scan_bsums<<<1, 256, 0, stream>>>(bsum, boff);
    scan_apply<<<NCHUNK, 256, 0, stream>>>(counts, boff, row_off, cursor, invdeg);
    fill_kernel<<<(N_EDGES + 255) / 256, 256, 0, stream>>>(ei, cursor, csr_src);
    pack_w1<<<256, 256, 0, stream>>>(W1l, W1r, Wpk1);
    pack_w2n<<<128, 256, 0, stream>>>(W2l, W2r, Wpk2n);
    conv_x16<<<(N_NODES * F_IN / 4 + 255) / 256, 256, 0, stream>>>(x, x16);
    gemm1_fused<<<N_NODES / 16, 256, 0, stream>>>(x16, row_off, csr_src, invdeg, Wpk1, b1, h16);
    proj2<<<N_NODES / 16, 256, 0, stream>>>(h16, Wpk2n, b2, hWl, hWr);
    k2b<<<N_NODES / 16, 256, 0, stream>>>(hWl, hWr, row_off, csr_src, invdeg, out);
}